// Round 1
// baseline (184.624 us; speedup 1.0000x reference)
//
#include <hip/hip_runtime.h>

// Depthwise 7x7 VALID conv, fp32, NCHW.
// x: (16,256,128,128), w: (256,7,7), out: (16,256,122,122)

#define BATCH 16
#define CHAN  256
#define H_IN  128
#define W_IN  128
#define KS    7
#define H_OUT 122
#define W_OUT 122

#define TILE   64          // output tile edge (64x64 per block)
#define IN_T   70          // input tile edge needed: TILE + KS - 1
#define LDSW   72          // LDS row stride in floats (16B-aligned rows)
#define VROW   18          // float4 chunks per staged row (72 floats)

__global__ __launch_bounds__(256, 2)
void dwconv7x7_kernel(const float* __restrict__ x,
                      const float* __restrict__ w,
                      float* __restrict__ out) {
    __shared__ float s_in[IN_T * LDSW];   // 70*72*4 = 20160 B

    const int img = blockIdx.z;                 // b*CHAN + c
    const int ch  = img & (CHAN - 1);
    const int x0  = blockIdx.x * TILE;          // output tile origin
    const int y0  = blockIdx.y * TILE;
    const int tid = threadIdx.x;

    // ---- stage input tile: rows y0..y0+69, cols x0..x0+71 (float4) ----
    const float* __restrict__ xp = x + (size_t)img * (H_IN * W_IN);
    for (int v = tid; v < IN_T * VROW; v += 256) {
        const int r  = v / VROW;
        const int c4 = v - r * VROW;
        const int gy = y0 + r;
        const int gx = x0 + c4 * 4;
        float4 val = make_float4(0.f, 0.f, 0.f, 0.f);
        if (gy < H_IN && gx + 3 < W_IN) {       // W_IN multiple of 4: no partials
            val = *reinterpret_cast<const float4*>(xp + gy * W_IN + gx);
        }
        *reinterpret_cast<float4*>(&s_in[r * LDSW + c4 * 4]) = val;
    }

    // ---- weights: uniform address -> scalar loads into SGPRs ----
    const float* __restrict__ wp = w + ch * (KS * KS);
    float wr[KS * KS];
    #pragma unroll
    for (int i = 0; i < KS * KS; ++i) wr[i] = wp[i];

    __syncthreads();

    // ---- compute: each thread owns a 4x4 output micro-tile ----
    const int tx  = tid & 15;     // 16 col-groups
    const int ty  = tid >> 4;     // 16 row-groups
    const int ox0 = tx * 4;       // block-relative output col
    const int oy0 = ty * 4;       // block-relative output row

    float acc[4][4] = {};

    #pragma unroll
    for (int r = 0; r < 10; ++r) {            // input rows oy0+r
        const float* rp = &s_in[(oy0 + r) * LDSW + ox0];
        float4 a0 = *reinterpret_cast<const float4*>(rp);
        float4 a1 = *reinterpret_cast<const float4*>(rp + 4);
        float4 a2 = *reinterpret_cast<const float4*>(rp + 8);
        const float in_row[12] = {a0.x, a0.y, a0.z, a0.w,
                                  a1.x, a1.y, a1.z, a1.w,
                                  a2.x, a2.y, a2.z, a2.w};
        #pragma unroll
        for (int i = 0; i < 4; ++i) {         // output row index in micro-tile
            const int ky = r - i;
            if (ky >= 0 && ky < KS) {
                #pragma unroll
                for (int kx = 0; kx < KS; ++kx) {
                    const float wv = wr[ky * KS + kx];
                    #pragma unroll
                    for (int cc = 0; cc < 4; ++cc) {
                        acc[i][cc] = fmaf(in_row[cc + kx], wv, acc[i][cc]);
                    }
                }
            }
        }
    }

    // ---- store ----
    float* __restrict__ op = out + (size_t)img * (H_OUT * W_OUT);
    const int gox = x0 + ox0;
    const int goy = y0 + oy0;
    #pragma unroll
    for (int i = 0; i < 4; ++i) {
        const int oy = goy + i;
        if (oy < H_OUT) {
            #pragma unroll
            for (int cc = 0; cc < 4; ++cc) {
                const int ox = gox + cc;
                if (ox < W_OUT) op[(size_t)oy * W_OUT + ox] = acc[i][cc];
            }
        }
    }
}

extern "C" void kernel_launch(void* const* d_in, const int* in_sizes, int n_in,
                              void* d_out, int out_size, void* d_ws, size_t ws_size,
                              hipStream_t stream) {
    const float* x = (const float*)d_in[0];
    const float* w = (const float*)d_in[1];
    float* out = (float*)d_out;

    dim3 grid(2, 2, BATCH * CHAN);   // 2x2 output tiles of 64x64 per 128x128 image
    dim3 block(256, 1, 1);
    dwconv7x7_kernel<<<grid, block, 0, stream>>>(x, w, out);
}